// Round 1
// baseline (1387.097 us; speedup 1.0000x reference)
//
#include <hip/hip_runtime.h>

// ---------------------------------------------------------------------------
// Per-pixel patch MLP, affine sub-chains collapsed offline (setup kernel).
//   sw(75) -> x1(50) -> [h1,lrelu,h2]tanh-> x3(75) -> E(3) + F(x1)(3)
//   -> lrelu -> D(50) -> [h4,tanh,h5] -> x6(50)=.. - x1 -> out(3), lrelu
// One thread per pixel; weights in LDS; activations in registers.
// ---------------------------------------------------------------------------

#define IW 384
#define HW (384 * 384)          // 147456
#define NPIX (4 * HW)           // 589824
#define BLOCK 512
#define GRID (NPIX / BLOCK)     // 1152

// packed weight layout in d_ws (floats), row strides padded to multiples of 4
#define OFF_WtA   0             // [75][52]  W_input^T (k-major)
#define OFF_bA    3900          // [52]
#define OFF_Wh1   3952          // [75][52]  W_h1 rows (j-major, k<50)
#define OFF_bh1   7852          // [76]
#define OFF_Wth2  7928          // [75][76]  W_h2^T (j-major, m<75)
#define OFF_bh2   13628         // [76]
#define OFF_E     13704         // [3][76]
#define OFF_be    13932         // [4]
#define OFF_F     13936         // [3][52]
#define OFF_bf    14092         // [4]
#define OFF_D     14096         // [50][4]
#define OFF_bd    14296         // [52]
#define OFF_Wh4   14348         // [125][52]
#define OFF_bh4   20848         // [128]
#define OFF_Wth5  20976         // [125][52]  W_h5^T (j-major, m<50)
#define OFF_bh5   27476         // [52]
#define OFF_Wout  27528         // [3][52]
#define OFF_bout  27684         // [4]
#define TOTAL_W   27688         // floats = 110752 bytes

__device__ __forceinline__ float lrelu(float v) {
    return v >= 0.0f ? v : 0.01f * v;
}

__device__ __forceinline__ float tanh_fast(float v) {
    // tanh(v) = 1 - 2/(exp(2v)+1); saturates correctly for |v| large.
    float e = __expf(2.0f * v);
    return 1.0f - 2.0f * __builtin_amdgcn_rcpf(e + 1.0f);
}

// ---------------------------------------------------------------------------
// Setup: collapse affine chains, transpose, pad, pack into ws.
// One block of 256 threads.
// ---------------------------------------------------------------------------
__global__ void setup_pack(
    const float* __restrict__ W_input, const float* __restrict__ b_input,
    const float* __restrict__ W_h1,  const float* __restrict__ b_h1,
    const float* __restrict__ W_h2,  const float* __restrict__ b_h2,
    const float* __restrict__ W_h3,  const float* __restrict__ b_h3,
    const float* __restrict__ W_h4,  const float* __restrict__ b_h4,
    const float* __restrict__ W_h5,  const float* __restrict__ b_h5,
    const float* __restrict__ W_out, const float* __restrict__ b_out,
    const float* __restrict__ W_e1,  const float* __restrict__ b_e1,
    const float* __restrict__ W_e2,  const float* __restrict__ b_e2,
    const float* __restrict__ W_e3,  const float* __restrict__ b_e3,
    const float* __restrict__ W_f1,  const float* __restrict__ b_f1,
    const float* __restrict__ W_f2,  const float* __restrict__ b_f2,
    const float* __restrict__ W_f3,  const float* __restrict__ b_f3,
    const float* __restrict__ W_d1,  const float* __restrict__ b_d1,
    const float* __restrict__ W_d2,  const float* __restrict__ b_d2,
    const float* __restrict__ W_d3,  const float* __restrict__ b_d3,
    float* __restrict__ ws)
{
    __shared__ float M1[675];   // W_e3 @ W_e2            (3 x 225)
    __shared__ float MF[450];   // W_f3 @ W_f2            (3 x 150)
    __shared__ float A1[450];   // W_d2 @ W_d1            (150 x 3)
    __shared__ float A2[150];   // W_d3 @ A1              (50 x 3)
    __shared__ float ue[75];    // W_e2 @ b_e1 + b_e2
    __shared__ float uf[50];    // W_f2 @ b_f1 + b_f2
    __shared__ float v1[150];   // W_d2 @ b_d1 + b_d2
    __shared__ float v2[50];    // W_d3 @ v1  + b_d3

    const int tid = threadIdx.x;
    const int NT  = 256;

    // zero whole packed region (pads) first
    for (int o = tid; o < TOTAL_W; o += NT) ws[o] = 0.0f;
    __syncthreads();

    // ---- plain copies / transposes (padded strides) ----
    for (int o = tid; o < 3750; o += NT) { int k = o / 50, j = o % 50; ws[OFF_WtA + k * 52 + j] = W_input[j * 75 + k]; }
    for (int o = tid; o < 50;   o += NT) ws[OFF_bA + o] = b_input[o];
    for (int o = tid; o < 3750; o += NT) { int j = o / 50, k = o % 50; ws[OFF_Wh1 + j * 52 + k] = W_h1[j * 50 + k]; }
    for (int o = tid; o < 75;   o += NT) ws[OFF_bh1 + o] = b_h1[o];
    for (int o = tid; o < 5625; o += NT) { int j = o / 75, m = o % 75; ws[OFF_Wth2 + j * 76 + m] = W_h2[m * 75 + j]; }
    for (int o = tid; o < 75;   o += NT) ws[OFF_bh2 + o] = b_h2[o];
    for (int o = tid; o < 6250; o += NT) { int j = o / 50, k = o % 50; ws[OFF_Wh4 + j * 52 + k] = W_h4[j * 50 + k]; }
    for (int o = tid; o < 125;  o += NT) ws[OFF_bh4 + o] = b_h4[o];
    for (int o = tid; o < 6250; o += NT) { int j = o / 50, m = o % 50; ws[OFF_Wth5 + j * 52 + m] = W_h5[m * 125 + j]; }
    for (int o = tid; o < 50;   o += NT) ws[OFF_bh5 + o] = b_h5[o];
    for (int o = tid; o < 150;  o += NT) { int c = o / 50, k = o % 50; ws[OFF_Wout + c * 52 + k] = W_out[c * 50 + k]; }
    for (int o = tid; o < 3;    o += NT) ws[OFF_bout + o] = b_out[o];

    // ---- stage 1: temps from raw inputs ----
    for (int o = tid; o < 675; o += NT) {
        int r = o / 225, c = o % 225; float s = 0.0f;
        for (int t = 0; t < 75; t++) s += W_e3[r * 75 + t] * W_e2[t * 225 + c];
        M1[o] = s;
    }
    for (int o = tid; o < 450; o += NT) {
        int r = o / 150, c = o % 150; float s = 0.0f;
        for (int t = 0; t < 50; t++) s += W_f3[r * 50 + t] * W_f2[t * 150 + c];
        MF[o] = s;
    }
    for (int o = tid; o < 450; o += NT) {
        int r = o / 3, c = o % 3; float s = 0.0f;
        for (int t = 0; t < 50; t++) s += W_d2[r * 50 + t] * W_d1[t * 3 + c];
        A1[o] = s;
    }
    for (int o = tid; o < 75; o += NT) {
        float s = b_e2[o];
        for (int t = 0; t < 225; t++) s += W_e2[o * 225 + t] * b_e1[t];
        ue[o] = s;
    }
    for (int o = tid; o < 50; o += NT) {
        float s = b_f2[o];
        for (int t = 0; t < 150; t++) s += W_f2[o * 150 + t] * b_f1[t];
        uf[o] = s;
    }
    for (int o = tid; o < 150; o += NT) {
        float s = b_d2[o];
        for (int t = 0; t < 50; t++) s += W_d2[o * 50 + t] * b_d1[t];
        v1[o] = s;
    }
    __syncthreads();

    // ---- stage 2 ----
    for (int o = tid; o < 225; o += NT) {   // E = M1 @ W_e1  (3 x 75)
        int r = o / 75, c = o % 75; float s = 0.0f;
        for (int t = 0; t < 225; t++) s += M1[r * 225 + t] * W_e1[t * 75 + c];
        ws[OFF_E + r * 76 + c] = s;
    }
    for (int o = tid; o < 3; o += NT) {     // be = W_e3 @ ue + b_e3
        float s = b_e3[o];
        for (int t = 0; t < 75; t++) s += W_e3[o * 75 + t] * ue[t];
        ws[OFF_be + o] = s;
    }
    for (int o = tid; o < 150; o += NT) {   // F = MF @ W_f1  (3 x 50)
        int r = o / 50, c = o % 50; float s = 0.0f;
        for (int t = 0; t < 150; t++) s += MF[r * 150 + t] * W_f1[t * 50 + c];
        ws[OFF_F + r * 52 + c] = s;
    }
    for (int o = tid; o < 3; o += NT) {     // bf = W_f3 @ uf + b_f3
        float s = b_f3[o];
        for (int t = 0; t < 50; t++) s += W_f3[o * 50 + t] * uf[t];
        ws[OFF_bf + o] = s;
    }
    for (int o = tid; o < 150; o += NT) {   // A2 = W_d3 @ A1 (50 x 3)
        int r = o / 3, c = o % 3; float s = 0.0f;
        for (int t = 0; t < 150; t++) s += W_d3[r * 150 + t] * A1[t * 3 + c];
        A2[o] = s;
    }
    for (int o = tid; o < 50; o += NT) {    // v2 = W_d3 @ v1 + b_d3
        float s = b_d3[o];
        for (int t = 0; t < 150; t++) s += W_d3[o * 150 + t] * v1[t];
        v2[o] = s;
    }
    __syncthreads();

    // ---- stage 3 ----
    for (int o = tid; o < 150; o += NT) {   // D = W_h3 @ A2 (50 x 3)
        int r = o / 3, c = o % 3; float s = 0.0f;
        for (int t = 0; t < 50; t++) s += W_h3[r * 50 + t] * A2[t * 3 + c];
        ws[OFF_D + r * 4 + c] = s;
    }
    for (int o = tid; o < 50; o += NT) {    // bd = W_h3 @ v2 + b_h3
        float s = b_h3[o];
        for (int t = 0; t < 50; t++) s += W_h3[o * 50 + t] * v2[t];
        ws[OFF_bd + o] = s;
    }
}

// ---------------------------------------------------------------------------
// Main fused kernel: one thread per pixel.
// ---------------------------------------------------------------------------
__global__ __launch_bounds__(BLOCK) void fused_mlp(
    const float* __restrict__ xin,   // (4,3,384,384)
    const float* __restrict__ wp,    // packed weights (TOTAL_W floats)
    float* __restrict__ out)         // (4,3,384,384)
{
    __shared__ __align__(16) float w[TOTAL_W];
    for (int i = threadIdx.x; i < TOTAL_W; i += BLOCK) w[i] = wp[i];
    __syncthreads();

    const int idx = blockIdx.x * BLOCK + threadIdx.x;   // < NPIX (exact grid)
    const int bb = idx / HW;
    const int p  = idx - bb * HW;
    const int y  = p / IW;
    const int x0 = p - y * IW;
    const float* __restrict__ xb = xin + bb * 3 * HW;

    // ---------------- stage A: x1 = W_input @ sw + b ----------------
    float x1[50];
#pragma unroll
    for (int j = 0; j < 50; j++) x1[j] = w[OFF_bA + j];
    {
        int wo = OFF_WtA;
#pragma unroll 1
        for (int c = 0; c < 3; c++) {
            const float* xc = xb + c * HW;
#pragma unroll 1
            for (int kh = 0; kh < 5; kh++) {
                int yy = y - 2 + kh;
                yy = yy < 0 ? -yy : (yy > 383 ? 766 - yy : yy);
                const float* xr = xc + yy * IW;
#pragma unroll
                for (int kw = 0; kw < 5; kw++) {
                    int xx = x0 - 2 + kw;
                    xx = xx < 0 ? -xx : (xx > 383 ? 766 - xx : xx);
                    const float s = xr[xx];
#pragma unroll
                    for (int j = 0; j < 50; j++) x1[j] = fmaf(w[wo + j], s, x1[j]);
                    wo += 52;
                }
            }
        }
    }

    // ------- stage B: x3 = tanh(W_h2 @ lrelu(W_h1 @ x1 + b1) + b2) -------
    float x3[75];
#pragma unroll
    for (int m = 0; m < 75; m++) x3[m] = 0.0f;
#pragma unroll 1
    for (int j = 0; j < 75; j++) {
        const int r1 = OFF_Wh1 + j * 52;
        float d0 = 0.f, d1 = 0.f, d2 = 0.f, d3 = 0.f;
#pragma unroll
        for (int k = 0; k < 48; k += 4) {
            d0 = fmaf(w[r1 + k],     x1[k],     d0);
            d1 = fmaf(w[r1 + k + 1], x1[k + 1], d1);
            d2 = fmaf(w[r1 + k + 2], x1[k + 2], d2);
            d3 = fmaf(w[r1 + k + 3], x1[k + 3], d3);
        }
        d0 = fmaf(w[r1 + 48], x1[48], d0);
        d1 = fmaf(w[r1 + 49], x1[49], d1);
        float u = w[OFF_bh1 + j] + ((d0 + d1) + (d2 + d3));
        u = lrelu(u);
        const int r2 = OFF_Wth2 + j * 76;
#pragma unroll
        for (int m = 0; m < 75; m++) x3[m] = fmaf(w[r2 + m], u, x3[m]);
    }
#pragma unroll
    for (int m = 0; m < 75; m++) x3[m] = tanh_fast(x3[m] + w[OFF_bh2 + m]);

    // ------- stage C: x4 = lrelu(E@x3+be + F@x1+bf); xd = D@x4 + bd -------
    float x4[3];
#pragma unroll
    for (int c = 0; c < 3; c++) {
        const int re = OFF_E + c * 76;
        float a0 = 0.f, a1 = 0.f, a2 = 0.f;
#pragma unroll
        for (int k = 0; k < 75; k += 3) {
            a0 = fmaf(w[re + k],     x3[k],     a0);
            a1 = fmaf(w[re + k + 1], x3[k + 1], a1);
            a2 = fmaf(w[re + k + 2], x3[k + 2], a2);
        }
        float e = w[OFF_be + c] + (a0 + (a1 + a2));
        const int rf = OFF_F + c * 52;
        float b0 = 0.f, b1 = 0.f;
#pragma unroll
        for (int k = 0; k < 50; k += 2) {
            b0 = fmaf(w[rf + k],     x1[k],     b0);
            b1 = fmaf(w[rf + k + 1], x1[k + 1], b1);
        }
        float f = w[OFF_bf + c] + (b0 + b1);
        x4[c] = lrelu(e + f);
    }
    float xd[50];
#pragma unroll
    for (int m = 0; m < 50; m++) {
        const int rd = OFF_D + m * 4;
        xd[m] = fmaf(w[rd + 2], x4[2], fmaf(w[rd + 1], x4[1], fmaf(w[rd], x4[0], w[OFF_bd + m])));
    }

    // ------- stage D: x6 = W_h5 @ tanh(W_h4 @ xd + b4) + b5 - x1 -------
    float x6[50];
#pragma unroll
    for (int m = 0; m < 50; m++) x6[m] = w[OFF_bh5 + m] - x1[m];
#pragma unroll 1
    for (int j = 0; j < 125; j++) {
        const int r4 = OFF_Wh4 + j * 52;
        float d0 = 0.f, d1 = 0.f, d2 = 0.f, d3 = 0.f;
#pragma unroll
        for (int k = 0; k < 48; k += 4) {
            d0 = fmaf(w[r4 + k],     xd[k],     d0);
            d1 = fmaf(w[r4 + k + 1], xd[k + 1], d1);
            d2 = fmaf(w[r4 + k + 2], xd[k + 2], d2);
            d3 = fmaf(w[r4 + k + 3], xd[k + 3], d3);
        }
        d0 = fmaf(w[r4 + 48], xd[48], d0);
        d1 = fmaf(w[r4 + 49], xd[49], d1);
        float t = w[OFF_bh4 + j] + ((d0 + d1) + (d2 + d3));
        t = tanh_fast(t);
        const int r5 = OFF_Wth5 + j * 52;
#pragma unroll
        for (int m = 0; m < 50; m++) x6[m] = fmaf(w[r5 + m], t, x6[m]);
    }

    // ------- stage E: out = lrelu(W_out @ x6 + b), store transposed -------
#pragma unroll
    for (int c = 0; c < 3; c++) {
        const int ro = OFF_Wout + c * 52;
        float a0 = 0.f, a1 = 0.f;
#pragma unroll
        for (int k = 0; k < 50; k += 2) {
            a0 = fmaf(w[ro + k],     x6[k],     a0);
            a1 = fmaf(w[ro + k + 1], x6[k + 1], a1);
        }
        float v = w[OFF_bout + c] + (a0 + a1);
        out[(bb * 3 + c) * HW + p] = lrelu(v);
    }
}

extern "C" void kernel_launch(void* const* d_in, const int* in_sizes, int n_in,
                              void* d_out, int out_size, void* d_ws, size_t ws_size,
                              hipStream_t stream)
{
    const float* xin = (const float*)d_in[0];
    float* ws = (float*)d_ws;

    setup_pack<<<1, 256, 0, stream>>>(
        (const float*)d_in[1],  (const float*)d_in[2],   // input
        (const float*)d_in[3],  (const float*)d_in[4],   // h1
        (const float*)d_in[5],  (const float*)d_in[6],   // h2
        (const float*)d_in[7],  (const float*)d_in[8],   // h3
        (const float*)d_in[9],  (const float*)d_in[10],  // h4
        (const float*)d_in[11], (const float*)d_in[12],  // h5
        (const float*)d_in[13], (const float*)d_in[14],  // out
        (const float*)d_in[15], (const float*)d_in[16],  // e1
        (const float*)d_in[17], (const float*)d_in[18],  // e2
        (const float*)d_in[19], (const float*)d_in[20],  // e3
        (const float*)d_in[21], (const float*)d_in[22],  // f1
        (const float*)d_in[23], (const float*)d_in[24],  // f2
        (const float*)d_in[25], (const float*)d_in[26],  // f3
        (const float*)d_in[27], (const float*)d_in[28],  // d1
        (const float*)d_in[29], (const float*)d_in[30],  // d2
        (const float*)d_in[31], (const float*)d_in[32],  // d3
        ws);

    fused_mlp<<<GRID, BLOCK, 0, stream>>>(xin, ws, (float*)d_out);
}